// Round 12
// baseline (195.762 us; speedup 1.0000x reference)
//
#include <hip/hip_runtime.h>

// Problem constants
#define BB 16
#define CC 128
#define MM 32
#define NN 16384   // H*W

// Workspace layout (float offsets)
#define WS_KV     0        // [16][32][32]
#define WS_KS     16384    // [16][32]
#define WS_SQ     16896    // [16][32]   sum_n Q'
#define WS_QQ     17408    // [16][32][32] sum_n Q'Q'^T
#define WS_YSUM   33792    // [128]
#define WS_YSQ    33920    // [128]
#define WS_ACCEND 34048    // zeroed region end
#define WS_SCALE  34048    // [128]
#define WS_BIAS   34176    // [128]
#define WS_W2     34304    // [16][128][32]

typedef __bf16 bf16x8 __attribute__((ext_vector_type(8)));
typedef float  f32x16 __attribute__((ext_vector_type(16)));

__device__ __forceinline__ float phi_f(float z) {
    // elu(z) + 1 (alpha=1): z>0 -> z+1 ; z<=0 -> exp(z)
    return z > 0.f ? z + 1.f : __expf(z);
}

// ---------------------------------------------------------------------------
// Projection via MFMA, wave-independent tiles, ZERO main-loop barriers.
// ROUND-12: round-7 kernel body (proven correct, 85 us at 2 blocks/CU) at
// grid (64,16) = 1024 blocks = 4 blocks/CU (VGPR 112 and LDS 36 KB both
// permit 4); each wave owns 2 tiles of 32 px. NO launch_bounds min-waves:
// r8 proved forcing occupancy via launch_bounds crushes VGPR -> spills
// (FETCH 151 MB scratch signature). TLP doubling is free here.
// Per tile: B-frags loaded straight from global (coalesced 128B/half-wave),
// split x = xh + xl in-register; A = bf16(W) rows (hi only; 2-term split:
// W x ~= Wh*Xh + Wh*Xl, err ~2^-9 relative).  Q/K/V share B-frags, 3
// interleaved accumulators.  phi(Q) -> d_out ch 0..31; K,V -> wave-private
// LDS -> in-wave fp32 KV/Ks outer-product accumulation.
__global__ __launch_bounds__(256) void projmfma_kernel(
    const float* __restrict__ x,
    const float* __restrict__ Wq, const float* __restrict__ Wk,
    const float* __restrict__ Wv,
    float* ws, float* __restrict__ qout)
{
    // per-wave K/V tiles (4 x (32*36*2) floats = 36 KB); reused for reduce
    __shared__ __align__(16) float lds[9216];

    const int b = blockIdx.y;
    const int t = threadIdx.x;
    const int w = t >> 6;          // wave id
    const int l = t & 63;
    const int g = l >> 5;          // k-slice half (0/1)
    const int ln31 = l & 31;       // A row (m) / B col (px) / D col (px)

    float* ktile = lds + w * 2304;          // [32][36]
    float* vtile = lds + w * 2304 + 1152;   // [32][36]

    // ---- W hi fragments (A-operand), all 3 matrices, loop-invariant
    bf16x8 wq[8], wk[8], wv[8];
    #pragma unroll
    for (int kt = 0; kt < 8; ++kt) {
        const int k0 = 16 * kt + 8 * g;
        #pragma unroll
        for (int j = 0; j < 8; ++j) {
            wq[kt][j] = (__bf16)Wq[ln31 * CC + k0 + j];
            wk[kt][j] = (__bf16)Wk[ln31 * CC + k0 + j];
            wv[kt][j] = (__bf16)Wv[ln31 * CC + k0 + j];
        }
    }

    // KV outer-product accumulator mapping (4x4 subtile per lane)
    const int m0 = (l >> 3) << 2;
    const int v0 = (l & 7) << 2;
    float kvacc[16];
    #pragma unroll
    for (int i = 0; i < 16; ++i) kvacc[i] = 0.f;
    float ksacc[4] = {0.f, 0.f, 0.f, 0.f};

    const int n0w = (blockIdx.x << 8) + (w << 6);   // wave's 64-px base

    for (int tile = 0; tile < 2; ++tile) {
        const int n0 = n0w + (tile << 5);

        // ---- load this lane's B-frags from global, split hi/lo in-register
        const float* xp = x + (size_t)b * CC * NN + n0 + ln31;
        bf16x8 bh[8], bl[8];
        #pragma unroll
        for (int kt = 0; kt < 8; ++kt) {
            const int k0 = 16 * kt + 8 * g;
            #pragma unroll
            for (int j = 0; j < 8; ++j) {
                const float f = xp[(k0 + j) * NN];
                const __bf16 h = (__bf16)f;
                bh[kt][j] = h;
                bl[kt][j] = (__bf16)(f - (float)h);
            }
        }

        // ---- MFMA: 3 interleaved accumulators, 2-term split
        f32x16 aq, ak, av;
        #pragma unroll
        for (int i = 0; i < 16; ++i) { aq[i] = 0.f; ak[i] = 0.f; av[i] = 0.f; }
        #pragma unroll
        for (int kt = 0; kt < 8; ++kt) {
            aq = __builtin_amdgcn_mfma_f32_32x32x16_bf16(wq[kt], bh[kt], aq, 0, 0, 0);
            ak = __builtin_amdgcn_mfma_f32_32x32x16_bf16(wk[kt], bh[kt], ak, 0, 0, 0);
            av = __builtin_amdgcn_mfma_f32_32x32x16_bf16(wv[kt], bh[kt], av, 0, 0, 0);
            aq = __builtin_amdgcn_mfma_f32_32x32x16_bf16(wq[kt], bl[kt], aq, 0, 0, 0);
            ak = __builtin_amdgcn_mfma_f32_32x32x16_bf16(wk[kt], bl[kt], ak, 0, 0, 0);
            av = __builtin_amdgcn_mfma_f32_32x32x16_bf16(wv[kt], bl[kt], av, 0, 0, 0);
        }

        // ---- D mapping: col(px) = lane&31, row = (reg&3)+8*(reg>>2)+4*g
        float* qp = qout + (size_t)b * CC * NN + n0 + ln31;
        #pragma unroll
        for (int i = 0; i < 16; ++i) {
            const int r = (i & 3) + 8 * (i >> 2) + 4 * g;
            qp[(size_t)r * NN] = phi_f(aq[i]);
        }
        #pragma unroll
        for (int i = 0; i < 16; ++i) {
            const int r = (i & 3) + 8 * (i >> 2) + 4 * g;
            ktile[ln31 * 36 + r] = phi_f(ak[i]);
            vtile[ln31 * 36 + r] = av[i];
        }
        // wave-private LDS: in-wave ds_write -> ds_read needs no barrier
        // (lockstep wave + compiler lgkmcnt), so proceed directly.

        // ---- fp32 KV/Ks rank-32 update over this wave's own 32 px
        #pragma unroll 8
        for (int p = 0; p < 32; ++p) {
            const float4 kf = *(const float4*)&ktile[p * 36 + m0];
            const float4 vf = *(const float4*)&vtile[p * 36 + v0];
            kvacc[ 0] = fmaf(kf.x, vf.x, kvacc[ 0]);
            kvacc[ 1] = fmaf(kf.x, vf.y, kvacc[ 1]);
            kvacc[ 2] = fmaf(kf.x, vf.z, kvacc[ 2]);
            kvacc[ 3] = fmaf(kf.x, vf.w, kvacc[ 3]);
            kvacc[ 4] = fmaf(kf.y, vf.x, kvacc[ 4]);
            kvacc[ 5] = fmaf(kf.y, vf.y, kvacc[ 5]);
            kvacc[ 6] = fmaf(kf.y, vf.z, kvacc[ 6]);
            kvacc[ 7] = fmaf(kf.y, vf.w, kvacc[ 7]);
            kvacc[ 8] = fmaf(kf.z, vf.x, kvacc[ 8]);
            kvacc[ 9] = fmaf(kf.z, vf.y, kvacc[ 9]);
            kvacc[10] = fmaf(kf.z, vf.z, kvacc[10]);
            kvacc[11] = fmaf(kf.z, vf.w, kvacc[11]);
            kvacc[12] = fmaf(kf.w, vf.x, kvacc[12]);
            kvacc[13] = fmaf(kf.w, vf.y, kvacc[13]);
            kvacc[14] = fmaf(kf.w, vf.z, kvacc[14]);
            kvacc[15] = fmaf(kf.w, vf.w, kvacc[15]);
            if (v0 == 0) {
                ksacc[0] += kf.x; ksacc[1] += kf.y;
                ksacc[2] += kf.z; ksacc[3] += kf.w;
            }
        }
    }

    // ---- cross-wave reduce (LDS reused), one atomic per entry per block
    __syncthreads();
    #pragma unroll
    for (int i = 0; i < 16; ++i) lds[t * 17 + i] = kvacc[i];    // max 4350
    if (v0 == 0) {
        const int r = l >> 3;
        #pragma unroll
        for (int i = 0; i < 4; ++i) lds[4352 + (w * 8 + r) * 4 + i] = ksacc[i];
    }
    __syncthreads();
    if (t < 64) {
        float* kvb = ws + WS_KV + (b << 10);
        #pragma unroll
        for (int i = 0; i < 16; ++i) {
            const float s = lds[t*17+i] + lds[(t+64)*17+i] + lds[(t+128)*17+i] + lds[(t+192)*17+i];
            atomicAdd(&kvb[(m0 + (i >> 2)) * 32 + v0 + (i & 3)], s);
        }
    }
    if (t < 8) {
        #pragma unroll
        for (int i = 0; i < 4; ++i) {
            const float s = lds[4352 + t*4+i] + lds[4352 + (8+t)*4+i]
                          + lds[4352 + (16+t)*4+i] + lds[4352 + (24+t)*4+i];
            atomicAdd(&ws[WS_KS + (b << 5) + t * 4 + i], s);
        }
    }
}

// ---------------------------------------------------------------------------
// W2[b] = Wout (128x32) @ KV[b] (32x32)
__global__ __launch_bounds__(256) void w2_kernel(const float* __restrict__ Wout,
                                                 float* ws) {
    const int b = blockIdx.x;
    const float* kvb = ws + WS_KV + (b << 10);
    float* w2b = ws + WS_W2 + (b << 12);
    const int t = threadIdx.x;
    #pragma unroll
    for (int i = 0; i < 16; ++i) {
        const int o = (i << 8) + t;
        const int c = o >> 5, v = o & 31;
        float acc = 0.f;
        #pragma unroll
        for (int m = 0; m < 32; ++m)
            acc = fmaf(Wout[(c << 5) + m], kvb[(m << 5) + v], acc);
        w2b[o] = acc;
    }
}

// ---------------------------------------------------------------------------
// Pass C: read phi(Q), fold inv; accumulate Sq[b], QQ[b].
// grid (64,16) x 256, one 256-px tile per block.
__global__ __launch_bounds__(256) void qq_kernel(const float* qsrc, float* ws) {
    __shared__ __align__(16) float qt[256 * 36];

    const int b = blockIdx.y;
    const int t = threadIdx.x;
    const int l = t & 63;
    const int g = t >> 6;
    const int m0 = (l >> 3) << 2;
    const int v0 = (l & 7) << 2;

    float qqacc[16];
    #pragma unroll
    for (int i = 0; i < 16; ++i) qqacc[i] = 0.f;
    float sqacc[4] = {0.f, 0.f, 0.f, 0.f};

    const float* ksb = ws + WS_KS + (b << 5);

    const int n = (blockIdx.x << 8) + t;
    const float* qp = qsrc + (size_t)b * CC * NN + n;
    float qa[32];
    #pragma unroll
    for (int m = 0; m < 32; ++m) qa[m] = qp[(size_t)m * NN];

    float denom = 1e-6f;
    #pragma unroll
    for (int m = 0; m < 32; ++m) denom = fmaf(qa[m], ksb[m], denom);
    const float inv = 1.0f / (16384.0f * denom);
    #pragma unroll
    for (int m = 0; m < 32; ++m) qa[m] *= inv;

    #pragma unroll
    for (int q = 0; q < 8; ++q)
        *(float4*)&qt[t * 36 + 4*q] = *(float4*)&qa[4*q];
    __syncthreads();

    const int pbase = g << 6;
    for (int pp = 0; pp < 64; ++pp) {
        const int p = pbase + pp;
        const float4 uf = *(const float4*)&qt[p * 36 + m0];
        const float4 vf = *(const float4*)&qt[p * 36 + v0];
        qqacc[ 0] = fmaf(uf.x, vf.x, qqacc[ 0]);
        qqacc[ 1] = fmaf(uf.x, vf.y, qqacc[ 1]);
        qqacc[ 2] = fmaf(uf.x, vf.z, qqacc[ 2]);
        qqacc[ 3] = fmaf(uf.x, vf.w, qqacc[ 3]);
        qqacc[ 4] = fmaf(uf.y, vf.x, qqacc[ 4]);
        qqacc[ 5] = fmaf(uf.y, vf.y, qqacc[ 5]);
        qqacc[ 6] = fmaf(uf.y, vf.z, qqacc[ 6]);
        qqacc[ 7] = fmaf(uf.y, vf.w, qqacc[ 7]);
        qqacc[ 8] = fmaf(uf.z, vf.x, qqacc[ 8]);
        qqacc[ 9] = fmaf(uf.z, vf.y, qqacc[ 9]);
        qqacc[10] = fmaf(uf.z, vf.z, qqacc[10]);
        qqacc[11] = fmaf(uf.z, vf.w, qqacc[11]);
        qqacc[12] = fmaf(uf.w, vf.x, qqacc[12]);
        qqacc[13] = fmaf(uf.w, vf.y, qqacc[13]);
        qqacc[14] = fmaf(uf.w, vf.z, qqacc[14]);
        qqacc[15] = fmaf(uf.w, vf.w, qqacc[15]);
        if (v0 == 0) {
            sqacc[0] += uf.x; sqacc[1] += uf.y;
            sqacc[2] += uf.z; sqacc[3] += uf.w;
        }
    }

    __syncthreads();
    #pragma unroll
    for (int i = 0; i < 16; ++i) qt[t * 17 + i] = qqacc[i];
    if (v0 == 0) {
        const int r = l >> 3;
        #pragma unroll
        for (int i = 0; i < 4; ++i) qt[4352 + (g * 8 + r) * 4 + i] = sqacc[i];
    }
    __syncthreads();
    if (t < 64) {
        float* qqb = ws + WS_QQ + (b << 10);
        #pragma unroll
        for (int i = 0; i < 16; ++i) {
            const float s = qt[t*17+i] + qt[(t+64)*17+i] + qt[(t+128)*17+i] + qt[(t+192)*17+i];
            atomicAdd(&qqb[(m0 + (i >> 2)) * 32 + v0 + (i & 3)], s);
        }
    }
    if (t < 8) {
        #pragma unroll
        for (int i = 0; i < 4; ++i) {
            const float s = qt[4352 + t*4+i] + qt[4352 + (8+t)*4+i]
                          + qt[4352 + (16+t)*4+i] + qt[4352 + (24+t)*4+i];
            atomicAdd(&ws[WS_SQ + (b << 5) + t * 4 + i], s);
        }
    }
}

// ---------------------------------------------------------------------------
// BN stats from moments: ysum_c += w2b[c]·Sq_b ; ysq_c += w2b[c]·QQ_b·w2b[c]^T
__global__ __launch_bounds__(128) void bnstat_kernel(float* ws) {
    const int b = blockIdx.x;   // 16
    const int c = threadIdx.x;  // 128
    const float* w2c = ws + WS_W2 + (b << 12) + (c << 5);
    const float* sq  = ws + WS_SQ + (b << 5);
    const float* qq  = ws + WS_QQ + (b << 10);
    float w[32];
    #pragma unroll
    for (int v = 0; v < 32; ++v) w[v] = w2c[v];
    float mb = 0.f;
    #pragma unroll
    for (int v = 0; v < 32; ++v) mb = fmaf(w[v], sq[v], mb);
    float qf = 0.f;
    for (int u = 0; u < 32; ++u) {
        float tacc = 0.f;
        #pragma unroll
        for (int v = 0; v < 32; ++v) tacc = fmaf(qq[(u << 5) + v], w[v], tacc);
        qf = fmaf(w[u], tacc, qf);
    }
    atomicAdd(&ws[WS_YSUM + c], mb);
    atomicAdd(&ws[WS_YSQ + c], qf);
}

// ---------------------------------------------------------------------------
__global__ void finalize_kernel(const float* __restrict__ gamma,
                                const float* __restrict__ beta, float* ws) {
    const int c = threadIdx.x;  // 128
    const float invBN = 1.0f / 262144.0f;
    const float mean = ws[WS_YSUM + c] * invBN;
    const float var  = ws[WS_YSQ + c] * invBN - mean * mean;
    const float s = gamma[c] * rsqrtf(var + 1e-5f);
    ws[WS_SCALE + c] = s;
    ws[WS_BIAS + c]  = fmaf(-mean, s, beta[c]);
}

// ---------------------------------------------------------------------------
// Output: y[c,n] = scale_c * (w2b[c]·(inv*Q_n)) + bias_c, 1 pixel/thread.
// grid (64,16) x 256 -> 4096 waves. w2/scale/bias staged in LDS.
// Output stored NONTEMPORAL (never re-read; keeps Q stripes cache-resident).
// qsrc aliases out: each thread reads its own pixel's 32 Q values BEFORE any
// store; per-thread order is safe; blocks touch disjoint (b,n) ranges.
__global__ __launch_bounds__(256) void out_kernel(const float* qsrc, const float* ws,
                                                  float* out) {
    __shared__ __align__(16) float w2s[CC * MM];   // 16 KB
    __shared__ float scs[CC];
    __shared__ float bis[CC];

    const int b = blockIdx.y;
    const int t = threadIdx.x;

    const float* w2b = ws + WS_W2 + (b << 12);
    #pragma unroll
    for (int i = 0; i < 4; ++i) {
        const int idx = (i << 8) + t;
        *(float4*)&w2s[idx << 2] = *(const float4*)&w2b[idx << 2];
    }
    if (t < CC) {
        scs[t] = ws[WS_SCALE + t];
        bis[t] = ws[WS_BIAS + t];
    }

    const int n = (blockIdx.x << 8) + t;
    const float* ksb = ws + WS_KS + (b << 5);

    const float* qp = qsrc + (size_t)b * CC * NN + n;
    float qa[32];
    #pragma unroll
    for (int m = 0; m < 32; ++m) qa[m] = qp[(size_t)m * NN];

    float d0 = 1e-6f;
    #pragma unroll
    for (int m = 0; m < 32; ++m) d0 = fmaf(qa[m], ksb[m], d0);
    const float inv = 1.0f / (16384.0f * d0);
    #pragma unroll
    for (int m = 0; m < 32; ++m) qa[m] *= inv;

    __syncthreads();

    float* op = out + (size_t)b * CC * NN + n;
    #pragma unroll 4
    for (int c = 0; c < CC; ++c) {
        const float* wr = &w2s[c << 5];
        float a0 = 0.f, a1 = 0.f, a2 = 0.f, a3 = 0.f;
        #pragma unroll
        for (int q = 0; q < 8; ++q) {
            const float4 w = *(const float4*)&wr[q << 2];
            a0 = fmaf(w.x, qa[4*q+0], a0);
            a1 = fmaf(w.y, qa[4*q+1], a1);
            a2 = fmaf(w.z, qa[4*q+2], a2);
            a3 = fmaf(w.w, qa[4*q+3], a3);
        }
        const float r = fmaf(scs[c], (a0 + a1) + (a2 + a3), bis[c]);
        __builtin_nontemporal_store(r, &op[(size_t)c * NN]);
    }
}

// ---------------------------------------------------------------------------
extern "C" void kernel_launch(void* const* d_in, const int* in_sizes, int n_in,
                              void* d_out, int out_size, void* d_ws, size_t ws_size,
                              hipStream_t stream) {
    const float* x     = (const float*)d_in[0];
    const float* Wq    = (const float*)d_in[1];
    const float* Wk    = (const float*)d_in[2];
    const float* Wv    = (const float*)d_in[3];
    const float* Wout  = (const float*)d_in[4];
    const float* gamma = (const float*)d_in[5];
    const float* beta  = (const float*)d_in[6];
    float* ws  = (float*)d_ws;
    float* out = (float*)d_out;

    // zero accumulators (KV, Ks, Sq, QQ, ysum, ysq) every launch
    hipMemsetAsync(ws, 0, (size_t)WS_ACCEND * sizeof(float), stream);

    projmfma_kernel<<<dim3(64, 16), 256, 0, stream>>>(x, Wq, Wk, Wv, ws, out);
    w2_kernel<<<16, 256, 0, stream>>>(Wout, ws);
    qq_kernel<<<dim3(64, 16), 256, 0, stream>>>(out, ws);
    bnstat_kernel<<<16, 128, 0, stream>>>(ws);
    finalize_kernel<<<1, 128, 0, stream>>>(gamma, beta, ws);
    out_kernel<<<dim3(64, 16), 256, 0, stream>>>(out, ws, out);
}

// Round 13
// 143.058 us; speedup vs baseline: 1.3684x; 1.3684x over previous
//
#include <hip/hip_runtime.h>

// Problem constants
#define BB 16
#define CC 128
#define MM 32
#define NN 16384   // H*W

// Workspace layout (float offsets)
#define WS_KV     0        // [16][32][32]
#define WS_KS     16384    // [16][32]
#define WS_SQ     16896    // [16][32]   sum_n Q'
#define WS_QQ     17408    // [16][32][32] sum_n Q'Q'^T
#define WS_YSUM   33792    // [128]
#define WS_YSQ    33920    // [128]
#define WS_ACCEND 34048    // zeroed region end
#define WS_SCALE  34048    // [128]
#define WS_BIAS   34176    // [128]
#define WS_W2     34304    // [16][128][32]

typedef __bf16 bf16x8 __attribute__((ext_vector_type(8)));
typedef __bf16 bf16x4 __attribute__((ext_vector_type(4)));
typedef float  f32x16 __attribute__((ext_vector_type(16)));

union B8 { bf16x8 v8; bf16x4 v4[2]; };

__device__ __forceinline__ float phi_f(float z) {
    // elu(z) + 1 (alpha=1): z>0 -> z+1 ; z<=0 -> exp(z)
    return z > 0.f ? z + 1.f : __expf(z);
}

// ---------------------------------------------------------------------------
// Zero the ws accumulator region (replaces hipMemsetAsync fill kernel).
__global__ void zero_kernel(float* ws) {
    const int i = blockIdx.x * 256 + threadIdx.x;
    if (i < (WS_ACCEND / 4)) {
        float4 z; z.x = 0.f; z.y = 0.f; z.z = 0.f; z.w = 0.f;
        ((float4*)ws)[i] = z;
    }
}

// ---------------------------------------------------------------------------
// Fused projection via split-bf16 MFMA + fp32 KV/Ks accumulation.
// grid (32,16) x 256 (4 waves); 512 px/block in 16 tiles of 32.
// Single-barrier software pipeline (round-11, best measured ~78-81 us;
// proj is declared locally converged at this structure).
__global__ __launch_bounds__(256) void projmfma_kernel(
    const float* __restrict__ x,
    const float* __restrict__ Wq, const float* __restrict__ Wk,
    const float* __restrict__ Wv,
    float* ws, float* __restrict__ qout)
{
    __shared__ __align__(16) char smem[53248];
    __bf16* Xh  = (__bf16*)smem;                    // [2][4352]
    __bf16* Xl  = (__bf16*)(smem + 17408);          // [2][4352]
    float*  ktb = (float*)(smem + 34816);           // [2][1152]
    float*  vtb = (float*)(smem + 44032);           // [2][1152]
    float*  red = (float*)smem;                     // [256*17] epilogue only
    float*  ksred = ktb;                            // [128] epilogue only

    const int b = blockIdx.y;
    const int t = threadIdx.x;
    const int w = t >> 6;          // wave id
    const int l = t & 63;
    const int g = l >> 5;          // k-group within wave (0/1)
    const int ln31 = l & 31;       // A row / B col / D col

    // ---- W fragments in registers (waves 0..2), hi + lo
    bf16x8 wh[8], wl[8];
    if (w < 3) {
        const float* Wm = (w == 0) ? Wq : (w == 1) ? Wk : Wv;
        const float* wr = Wm + ln31 * CC;
        #pragma unroll
        for (int kt = 0; kt < 8; ++kt) {
            const int k0 = 16 * kt + 8 * g;
            #pragma unroll
            for (int j = 0; j < 8; ++j) {
                const float f = wr[k0 + j];
                const __bf16 h = (__bf16)f;
                wh[kt][j] = h;
                wl[kt][j] = (__bf16)(f - (float)h);
            }
        }
    }

    // KV outer-product accumulator mapping
    const int m0 = (l >> 3) << 2;
    const int v0 = (l & 7) << 2;
    float kvacc[16];
    #pragma unroll
    for (int i = 0; i < 16; ++i) kvacc[i] = 0.f;
    float ksacc[4] = {0.f, 0.f, 0.f, 0.f};

    const int px = t & 31;
    const int cb = t >> 5;        // 0..7

    const float* xbase = x + (size_t)b * CC * NN + (blockIdx.x << 9) + px;

    // ---- prologue: load + convert tile 0 into X[0]
    float xbuf[16];
    #pragma unroll
    for (int j = 0; j < 16; ++j)
        xbuf[j] = xbase[(size_t)(cb * 16 + j) * NN];
    {
        __bf16 hbuf[16], lbuf[16];
        #pragma unroll
        for (int j = 0; j < 16; ++j) {
            const float f = xbuf[j];
            const __bf16 h = (__bf16)f;
            hbuf[j] = h;
            lbuf[j] = (__bf16)(f - (float)h);
        }
        *(bf16x8*)&Xh[px * 136 + cb * 16]     = *(bf16x8*)&hbuf[0];
        *(bf16x8*)&Xh[px * 136 + cb * 16 + 8] = *(bf16x8*)&hbuf[8];
        *(bf16x8*)&Xl[px * 136 + cb * 16]     = *(bf16x8*)&lbuf[0];
        *(bf16x8*)&Xl[px * 136 + cb * 16 + 8] = *(bf16x8*)&lbuf[8];
    }
    __syncthreads();

    for (int tile = 0; tile < 16; ++tile) {
        const int cur = tile & 1;
        const int n0 = (blockIdx.x << 9) + (tile << 5);

        // ---- phase 1: loads(t+1) || MFMA(t) || KV(t-1)
        if (tile < 15) {
            const float* xp = xbase + ((tile + 1) << 5);
            #pragma unroll
            for (int j = 0; j < 16; ++j)
                xbuf[j] = xp[(size_t)(cb * 16 + j) * NN];
        }

        f32x16 acc;
        if (w < 3) {
            #pragma unroll
            for (int i = 0; i < 16; ++i) acc[i] = 0.f;
            const __bf16* xh = Xh + cur * 4352 + ln31 * 136;
            const __bf16* xl = Xl + cur * 4352 + ln31 * 136;
            #pragma unroll
            for (int kt = 0; kt < 8; ++kt) {
                const int k0 = 16 * kt + 8 * g;
                const bf16x8 bh = *(const bf16x8*)&xh[k0];
                const bf16x8 bl = *(const bf16x8*)&xl[k0];
                acc = __builtin_amdgcn_mfma_f32_32x32x16_bf16(wh[kt], bh, acc, 0, 0, 0);
                acc = __builtin_amdgcn_mfma_f32_32x32x16_bf16(wh[kt], bl, acc, 0, 0, 0);
                acc = __builtin_amdgcn_mfma_f32_32x32x16_bf16(wl[kt], bh, acc, 0, 0, 0);
            }
        }

        if (tile > 0) {
            const float* ktp = ktb + (cur ^ 1) * 1152;
            const float* vtp = vtb + (cur ^ 1) * 1152;
            const int pb = w << 3;
            #pragma unroll
            for (int pp = 0; pp < 8; ++pp) {
                const int p = pb + pp;
                const float4 kf = *(const float4*)&ktp[p * 36 + m0];
                const float4 vf = *(const float4*)&vtp[p * 36 + v0];
                kvacc[ 0] = fmaf(kf.x, vf.x, kvacc[ 0]);
                kvacc[ 1] = fmaf(kf.x, vf.y, kvacc[ 1]);
                kvacc[ 2] = fmaf(kf.x, vf.z, kvacc[ 2]);
                kvacc[ 3] = fmaf(kf.x, vf.w, kvacc[ 3]);
                kvacc[ 4] = fmaf(kf.y, vf.x, kvacc[ 4]);
                kvacc[ 5] = fmaf(kf.y, vf.y, kvacc[ 5]);
                kvacc[ 6] = fmaf(kf.y, vf.z, kvacc[ 6]);
                kvacc[ 7] = fmaf(kf.y, vf.w, kvacc[ 7]);
                kvacc[ 8] = fmaf(kf.z, vf.x, kvacc[ 8]);
                kvacc[ 9] = fmaf(kf.z, vf.y, kvacc[ 9]);
                kvacc[10] = fmaf(kf.z, vf.z, kvacc[10]);
                kvacc[11] = fmaf(kf.z, vf.w, kvacc[11]);
                kvacc[12] = fmaf(kf.w, vf.x, kvacc[12]);
                kvacc[13] = fmaf(kf.w, vf.y, kvacc[13]);
                kvacc[14] = fmaf(kf.w, vf.z, kvacc[14]);
                kvacc[15] = fmaf(kf.w, vf.w, kvacc[15]);
                if (v0 == 0) {
                    ksacc[0] += kf.x; ksacc[1] += kf.y;
                    ksacc[2] += kf.z; ksacc[3] += kf.w;
                }
            }
        }

        // ---- phase 2: write outputs of tile t, stage X for tile t+1
        if (w == 0) {
            float* qp = qout + (size_t)b * CC * NN + n0 + ln31;
            #pragma unroll
            for (int i = 0; i < 16; ++i) {
                const int r = (i & 3) + 8 * (i >> 2) + 4 * g;
                qp[(size_t)r * NN] = phi_f(acc[i]);
            }
        } else if (w == 1) {
            float* ktp = ktb + cur * 1152;
            #pragma unroll
            for (int i = 0; i < 16; ++i) {
                const int r = (i & 3) + 8 * (i >> 2) + 4 * g;
                ktp[ln31 * 36 + r] = phi_f(acc[i]);
            }
        } else if (w == 2) {
            float* vtp = vtb + cur * 1152;
            #pragma unroll
            for (int i = 0; i < 16; ++i) {
                const int r = (i & 3) + 8 * (i >> 2) + 4 * g;
                vtp[ln31 * 36 + r] = acc[i];
            }
        }

        if (tile < 15) {
            const int nxt = cur ^ 1;
            __bf16 hbuf[16], lbuf[16];
            #pragma unroll
            for (int j = 0; j < 16; ++j) {
                const float f = xbuf[j];
                const __bf16 h = (__bf16)f;
                hbuf[j] = h;
                lbuf[j] = (__bf16)(f - (float)h);
            }
            *(bf16x8*)&Xh[nxt * 4352 + px * 136 + cb * 16]     = *(bf16x8*)&hbuf[0];
            *(bf16x8*)&Xh[nxt * 4352 + px * 136 + cb * 16 + 8] = *(bf16x8*)&hbuf[8];
            *(bf16x8*)&Xl[nxt * 4352 + px * 136 + cb * 16]     = *(bf16x8*)&lbuf[0];
            *(bf16x8*)&Xl[nxt * 4352 + px * 136 + cb * 16 + 8] = *(bf16x8*)&lbuf[8];
        }
        __syncthreads();
    }

    // ---- epilogue: KV-outer for tile 15 (buffers kt[1]/vt[1])
    {
        const float* ktp = ktb + 1152;
        const float* vtp = vtb + 1152;
        const int pb = w << 3;
        #pragma unroll
        for (int pp = 0; pp < 8; ++pp) {
            const int p = pb + pp;
            const float4 kf = *(const float4*)&ktp[p * 36 + m0];
            const float4 vf = *(const float4*)&vtp[p * 36 + v0];
            kvacc[ 0] = fmaf(kf.x, vf.x, kvacc[ 0]);
            kvacc[ 1] = fmaf(kf.x, vf.y, kvacc[ 1]);
            kvacc[ 2] = fmaf(kf.x, vf.z, kvacc[ 2]);
            kvacc[ 3] = fmaf(kf.x, vf.w, kvacc[ 3]);
            kvacc[ 4] = fmaf(kf.y, vf.x, kvacc[ 4]);
            kvacc[ 5] = fmaf(kf.y, vf.y, kvacc[ 5]);
            kvacc[ 6] = fmaf(kf.y, vf.z, kvacc[ 6]);
            kvacc[ 7] = fmaf(kf.y, vf.w, kvacc[ 7]);
            kvacc[ 8] = fmaf(kf.z, vf.x, kvacc[ 8]);
            kvacc[ 9] = fmaf(kf.z, vf.y, kvacc[ 9]);
            kvacc[10] = fmaf(kf.z, vf.z, kvacc[10]);
            kvacc[11] = fmaf(kf.z, vf.w, kvacc[11]);
            kvacc[12] = fmaf(kf.w, vf.x, kvacc[12]);
            kvacc[13] = fmaf(kf.w, vf.y, kvacc[13]);
            kvacc[14] = fmaf(kf.w, vf.z, kvacc[14]);
            kvacc[15] = fmaf(kf.w, vf.w, kvacc[15]);
            if (v0 == 0) {
                ksacc[0] += kf.x; ksacc[1] += kf.y;
                ksacc[2] += kf.z; ksacc[3] += kf.w;
            }
        }
    }
    __syncthreads();

    // ---- cross-wave reduce (red overlays Xh region), one atomic per entry
    #pragma unroll
    for (int i = 0; i < 16; ++i) red[t * 17 + i] = kvacc[i];
    if (v0 == 0) {
        const int r = l >> 3;
        #pragma unroll
        for (int i = 0; i < 4; ++i) ksred[(w * 8 + r) * 4 + i] = ksacc[i];
    }
    __syncthreads();
    if (t < 64) {
        float* kvb = ws + WS_KV + (b << 10);
        #pragma unroll
        for (int i = 0; i < 16; ++i) {
            const float s = red[t*17+i] + red[(t+64)*17+i] + red[(t+128)*17+i] + red[(t+192)*17+i];
            atomicAdd(&kvb[(m0 + (i >> 2)) * 32 + v0 + (i & 3)], s);
        }
    }
    if (t < 8) {
        #pragma unroll
        for (int i = 0; i < 4; ++i) {
            const float s = ksred[t*4+i] + ksred[(8+t)*4+i] + ksred[(16+t)*4+i] + ksred[(24+t)*4+i];
            atomicAdd(&ws[WS_KS + (b << 5) + t * 4 + i], s);
        }
    }
}

// ---------------------------------------------------------------------------
// W2[b] = Wout (128x32) @ KV[b] (32x32)
__global__ __launch_bounds__(256) void w2_kernel(const float* __restrict__ Wout,
                                                 float* ws) {
    const int b = blockIdx.x;
    const float* kvb = ws + WS_KV + (b << 10);
    float* w2b = ws + WS_W2 + (b << 12);
    const int t = threadIdx.x;
    #pragma unroll
    for (int i = 0; i < 16; ++i) {
        const int o = (i << 8) + t;
        const int c = o >> 5, v = o & 31;
        float acc = 0.f;
        #pragma unroll
        for (int m = 0; m < 32; ++m)
            acc = fmaf(Wout[(c << 5) + m], kvb[(m << 5) + v], acc);
        w2b[o] = acc;
    }
}

// ---------------------------------------------------------------------------
// Pass C: read phi(Q), fold inv; accumulate Sq[b], QQ[b].
// grid (64,16) x 256, one 256-px tile per block.
__global__ __launch_bounds__(256) void qq_kernel(const float* qsrc, float* ws) {
    __shared__ __align__(16) float qt[256 * 36];

    const int b = blockIdx.y;
    const int t = threadIdx.x;
    const int l = t & 63;
    const int g = t >> 6;
    const int m0 = (l >> 3) << 2;
    const int v0 = (l & 7) << 2;

    float qqacc[16];
    #pragma unroll
    for (int i = 0; i < 16; ++i) qqacc[i] = 0.f;
    float sqacc[4] = {0.f, 0.f, 0.f, 0.f};

    const float* ksb = ws + WS_KS + (b << 5);

    const int n = (blockIdx.x << 8) + t;
    const float* qp = qsrc + (size_t)b * CC * NN + n;
    float qa[32];
    #pragma unroll
    for (int m = 0; m < 32; ++m) qa[m] = qp[(size_t)m * NN];

    float denom = 1e-6f;
    #pragma unroll
    for (int m = 0; m < 32; ++m) denom = fmaf(qa[m], ksb[m], denom);
    const float inv = 1.0f / (16384.0f * denom);
    #pragma unroll
    for (int m = 0; m < 32; ++m) qa[m] *= inv;

    #pragma unroll
    for (int q = 0; q < 8; ++q)
        *(float4*)&qt[t * 36 + 4*q] = *(float4*)&qa[4*q];
    __syncthreads();

    const int pbase = g << 6;
    for (int pp = 0; pp < 64; ++pp) {
        const int p = pbase + pp;
        const float4 uf = *(const float4*)&qt[p * 36 + m0];
        const float4 vf = *(const float4*)&qt[p * 36 + v0];
        qqacc[ 0] = fmaf(uf.x, vf.x, qqacc[ 0]);
        qqacc[ 1] = fmaf(uf.x, vf.y, qqacc[ 1]);
        qqacc[ 2] = fmaf(uf.x, vf.z, qqacc[ 2]);
        qqacc[ 3] = fmaf(uf.x, vf.w, qqacc[ 3]);
        qqacc[ 4] = fmaf(uf.y, vf.x, qqacc[ 4]);
        qqacc[ 5] = fmaf(uf.y, vf.y, qqacc[ 5]);
        qqacc[ 6] = fmaf(uf.y, vf.z, qqacc[ 6]);
        qqacc[ 7] = fmaf(uf.y, vf.w, qqacc[ 7]);
        qqacc[ 8] = fmaf(uf.z, vf.x, qqacc[ 8]);
        qqacc[ 9] = fmaf(uf.z, vf.y, qqacc[ 9]);
        qqacc[10] = fmaf(uf.z, vf.z, qqacc[10]);
        qqacc[11] = fmaf(uf.z, vf.w, qqacc[11]);
        qqacc[12] = fmaf(uf.w, vf.x, qqacc[12]);
        qqacc[13] = fmaf(uf.w, vf.y, qqacc[13]);
        qqacc[14] = fmaf(uf.w, vf.z, qqacc[14]);
        qqacc[15] = fmaf(uf.w, vf.w, qqacc[15]);
        if (v0 == 0) {
            sqacc[0] += uf.x; sqacc[1] += uf.y;
            sqacc[2] += uf.z; sqacc[3] += uf.w;
        }
    }

    __syncthreads();
    #pragma unroll
    for (int i = 0; i < 16; ++i) qt[t * 17 + i] = qqacc[i];
    if (v0 == 0) {
        const int r = l >> 3;
        #pragma unroll
        for (int i = 0; i < 4; ++i) qt[4352 + (g * 8 + r) * 4 + i] = sqacc[i];
    }
    __syncthreads();
    if (t < 64) {
        float* qqb = ws + WS_QQ + (b << 10);
        #pragma unroll
        for (int i = 0; i < 16; ++i) {
            const float s = qt[t*17+i] + qt[(t+64)*17+i] + qt[(t+128)*17+i] + qt[(t+192)*17+i];
            atomicAdd(&qqb[(m0 + (i >> 2)) * 32 + v0 + (i & 3)], s);
        }
    }
    if (t < 8) {
        #pragma unroll
        for (int i = 0; i < 4; ++i) {
            const float s = qt[4352 + t*4+i] + qt[4352 + (8+t)*4+i]
                          + qt[4352 + (16+t)*4+i] + qt[4352 + (24+t)*4+i];
            atomicAdd(&ws[WS_SQ + (b << 5) + t * 4 + i], s);
        }
    }
}

// ---------------------------------------------------------------------------
// BN stats from moments: ysum_c += w2b[c]·Sq_b ; ysq_c += w2b[c]·QQ_b·w2b[c]^T
__global__ __launch_bounds__(128) void bnstat_kernel(float* ws) {
    const int b = blockIdx.x;   // 16
    const int c = threadIdx.x;  // 128
    const float* w2c = ws + WS_W2 + (b << 12) + (c << 5);
    const float* sq  = ws + WS_SQ + (b << 5);
    const float* qq  = ws + WS_QQ + (b << 10);
    float w[32];
    #pragma unroll
    for (int v = 0; v < 32; ++v) w[v] = w2c[v];
    float mb = 0.f;
    #pragma unroll
    for (int v = 0; v < 32; ++v) mb = fmaf(w[v], sq[v], mb);
    float qf = 0.f;
    for (int u = 0; u < 32; ++u) {
        float tacc = 0.f;
        #pragma unroll
        for (int v = 0; v < 32; ++v) tacc = fmaf(qq[(u << 5) + v], w[v], tacc);
        qf = fmaf(w[u], tacc, qf);
    }
    atomicAdd(&ws[WS_YSUM + c], mb);
    atomicAdd(&ws[WS_YSQ + c], qf);
}

// ---------------------------------------------------------------------------
__global__ void finalize_kernel(const float* __restrict__ gamma,
                                const float* __restrict__ beta, float* ws) {
    const int c = threadIdx.x;  // 128
    const float invBN = 1.0f / 262144.0f;
    const float mean = ws[WS_YSUM + c] * invBN;
    const float var  = ws[WS_YSQ + c] * invBN - mean * mean;
    const float s = gamma[c] * rsqrtf(var + 1e-5f);
    ws[WS_SCALE + c] = s;
    ws[WS_BIAS + c]  = fmaf(-mean, s, beta[c]);
}

// ---------------------------------------------------------------------------
// Output via MFMA: y[c,n] = scale_c*(W2[c,:]·Q'_n) + bias_c for a 256-px tile.
// Per block: stage Q' (inv-folded) as bf16 hi/lo in LDS (stride-36 rows ->
// 2-way bank pattern, free); each wave computes its own 64 px (wave-private
// rows: thread t == px, so wave w wrote rows w*64..w*64+63 itself) x 128 c
// via 48 mfma_f32_32x32x16_bf16 (3-term split, rel err ~2^-16).
// Replaces the scalar version's 1024 ds_read_b128 + 4096 VALU FMA per thread.
// qsrc aliases out: all Q reads happen before the barrier; stores after.
__global__ __launch_bounds__(256) void out_kernel(const float* qsrc, const float* ws,
                                                  float* out) {
    __shared__ __align__(16) __bf16 Qh[256 * 36];  // 18 KB
    __shared__ __align__(16) __bf16 Ql[256 * 36];  // 18 KB
    __shared__ float scs[CC];
    __shared__ float bis[CC];

    const int b = blockIdx.y;
    const int t = threadIdx.x;
    const int w = t >> 6;
    const int l = t & 63;
    const int g = l >> 5;
    const int ln31 = l & 31;

    if (t < CC) {
        scs[t] = ws[WS_SCALE + t];
        bis[t] = ws[WS_BIAS + t];
    }

    const int n = (blockIdx.x << 8) + t;
    const float* ksb = ws + WS_KS + (b << 5);

    // ---- stage: load this px's Q, fold inv, convert to bf16 hi/lo in LDS
    const float* qp = qsrc + (size_t)b * CC * NN + n;
    float qa[32];
    #pragma unroll
    for (int m = 0; m < 32; ++m) qa[m] = qp[(size_t)m * NN];

    float d0 = 1e-6f;
    #pragma unroll
    for (int m = 0; m < 32; ++m) d0 = fmaf(qa[m], ksb[m], d0);
    const float inv = 1.0f / (16384.0f * d0);
    #pragma unroll
    for (int m = 0; m < 32; ++m) qa[m] *= inv;

    {
        __bf16 qh[32], ql[32];
        #pragma unroll
        for (int m = 0; m < 32; ++m) {
            const __bf16 h = (__bf16)qa[m];
            qh[m] = h;
            ql[m] = (__bf16)(qa[m] - (float)h);
        }
        #pragma unroll
        for (int i = 0; i < 8; ++i) {
            *(bf16x4*)&Qh[t * 36 + i * 4] = *(bf16x4*)&qh[i * 4];
            *(bf16x4*)&Ql[t * 36 + i * 4] = *(bf16x4*)&ql[i * 4];
        }
    }
    __syncthreads();

    const float* w2b = ws + WS_W2 + (b << 12);
    float* ob = out + (size_t)b * CC * NN + (blockIdx.x << 8);

    #pragma unroll
    for (int cb = 0; cb < 4; ++cb) {
        // A-frags: w2 rows c = cb*32 + ln31, k = v, hi + lo
        bf16x8 ah[2], al[2];
        #pragma unroll
        for (int kt = 0; kt < 2; ++kt) {
            const float* wp = w2b + (cb * 32 + ln31) * 32 + kt * 16 + g * 8;
            #pragma unroll
            for (int j = 0; j < 8; ++j) {
                const float f = wp[j];
                const __bf16 h = (__bf16)f;
                ah[kt][j] = h;
                al[kt][j] = (__bf16)(f - (float)h);
            }
        }
        #pragma unroll
        for (int pg = 0; pg < 2; ++pg) {
            const int px0 = (w << 6) + (pg << 5);    // wave-private rows
            f32x16 acc;
            #pragma unroll
            for (int i = 0; i < 16; ++i) acc[i] = 0.f;
            #pragma unroll
            for (int kt = 0; kt < 2; ++kt) {
                const int k0 = kt * 16 + g * 8;
                const __bf16* qhp = &Qh[(px0 + ln31) * 36 + k0];
                const __bf16* qlp = &Ql[(px0 + ln31) * 36 + k0];
                B8 bh, bl;
                bh.v4[0] = *(const bf16x4*)&qhp[0];
                bh.v4[1] = *(const bf16x4*)&qhp[4];
                bl.v4[0] = *(const bf16x4*)&qlp[0];
                bl.v4[1] = *(const bf16x4*)&qlp[4];
                acc = __builtin_amdgcn_mfma_f32_32x32x16_bf16(ah[kt], bh.v8, acc, 0, 0, 0);
                acc = __builtin_amdgcn_mfma_f32_32x32x16_bf16(ah[kt], bl.v8, acc, 0, 0, 0);
                acc = __builtin_amdgcn_mfma_f32_32x32x16_bf16(al[kt], bh.v8, acc, 0, 0, 0);
            }
            // D mapping: col = px0+ln31, row r = (i&3)+8*(i>>2)+4*g ; c = cb*32+r
            #pragma unroll
            for (int i = 0; i < 16; ++i) {
                const int r = (i & 3) + 8 * (i >> 2) + 4 * g;
                const int c = cb * 32 + r;
                const float v = fmaf(scs[c], acc[i], bis[c]);
                __builtin_nontemporal_store(v, &ob[(size_t)c * NN + px0 + ln31]);
            }
        }
    }
}

// ---------------------------------------------------------------------------
extern "C" void kernel_launch(void* const* d_in, const int* in_sizes, int n_in,
                              void* d_out, int out_size, void* d_ws, size_t ws_size,
                              hipStream_t stream) {
    const float* x     = (const float*)d_in[0];
    const float* Wq    = (const float*)d_in[1];
    const float* Wk    = (const float*)d_in[2];
    const float* Wv    = (const float*)d_in[3];
    const float* Wout  = (const float*)d_in[4];
    const float* gamma = (const float*)d_in[5];
    const float* beta  = (const float*)d_in[6];
    float* ws  = (float*)d_ws;
    float* out = (float*)d_out;

    // zero accumulators (KV, Ks, Sq, QQ, ysum, ysq) every launch
    zero_kernel<<<34, 256, 0, stream>>>(ws);

    projmfma_kernel<<<dim3(32, 16), 256, 0, stream>>>(x, Wq, Wk, Wv, ws, out);
    w2_kernel<<<16, 256, 0, stream>>>(Wout, ws);
    qq_kernel<<<dim3(64, 16), 256, 0, stream>>>(out, ws);
    bnstat_kernel<<<16, 128, 0, stream>>>(ws);
    finalize_kernel<<<1, 128, 0, stream>>>(gamma, beta, ws);
    out_kernel<<<dim3(64, 16), 256, 0, stream>>>(out, ws, out);
}

// Round 14
// 131.241 us; speedup vs baseline: 1.4916x; 1.0900x over previous
//
#include <hip/hip_runtime.h>

// Problem constants
#define BB 16
#define CC 128
#define MM 32
#define NN 16384   // H*W

// Workspace layout (float offsets)
#define WS_KV     0        // [16][32][32]
#define WS_KS     16384    // [16][32]
#define WS_SQ     16896    // [16][32]   sum_n Q'
#define WS_QQ     17408    // [16][32][32] sum_n Q'Q'^T
#define WS_YSUM   33792    // [128]
#define WS_YSQ    33920    // [128]
#define WS_ACCEND 34048    // zeroed region end
#define WS_SCALE  34048    // [128] (unused now)
#define WS_BIAS   34176    // [128] (unused now)
#define WS_W2     34304    // [16][128][32]

typedef __bf16 bf16x8 __attribute__((ext_vector_type(8)));
typedef __bf16 bf16x4 __attribute__((ext_vector_type(4)));
typedef float  f32x16 __attribute__((ext_vector_type(16)));

union B8 { bf16x8 v8; bf16x4 v4[2]; };

__device__ __forceinline__ float phi_f(float z) {
    // elu(z) + 1 (alpha=1): z>0 -> z+1 ; z<=0 -> exp(z)
    return z > 0.f ? z + 1.f : __expf(z);
}

// ---------------------------------------------------------------------------
// Zero the ws accumulator region.
__global__ void zero_kernel(float* ws) {
    const int i = blockIdx.x * 256 + threadIdx.x;
    if (i < (WS_ACCEND / 4)) {
        float4 z; z.x = 0.f; z.y = 0.f; z.z = 0.f; z.w = 0.f;
        ((float4*)ws)[i] = z;
    }
}

// ---------------------------------------------------------------------------
// Fused projection via split-bf16 MFMA; KV/Ks accumulated by WAVE 3 via MFMA.
// grid (32,16) x 256 (4 waves); 512 px/block in 16 tiles of 32.
// ROUND-14: wave specialization. Waves 0-2: proj MFMA (Q/K/V). Waves 1-2
// write K/V as bf16 hi/lo in TRANSPOSED [m][px] layout (stride 40). Wave 3
// (idle during proj MFMA before) accumulates KV[b] via 6 mfma/tile
// (3-term split) and Ks[b] via 4 mfma with a ones-B operand, in registers
// across all 16 tiles; direct atomics at the end. This removes the fp32
// KV-outer VALU loop (the largest VALU consumer) from all waves and the
// cross-wave LDS reduce epilogue entirely.
__global__ __launch_bounds__(256) void projmfma_kernel(
    const float* __restrict__ x,
    const float* __restrict__ Wq, const float* __restrict__ Wk,
    const float* __restrict__ Wv,
    float* ws, float* __restrict__ qout)
{
    // Xh[2][4352] | Xl[2][4352] bf16 ; ktH/ktL/vtH/vtL [2][32*40] bf16
    __shared__ __align__(16) char smem[55296];
    __bf16* Xh  = (__bf16*)smem;                    // 17408 B
    __bf16* Xl  = (__bf16*)(smem + 17408);          // 17408 B
    __bf16* ktH = (__bf16*)(smem + 34816);          // 5120 B
    __bf16* ktL = (__bf16*)(smem + 39936);          // 5120 B
    __bf16* vtH = (__bf16*)(smem + 45056);          // 5120 B
    __bf16* vtL = (__bf16*)(smem + 50176);          // 5120 B

    const int b = blockIdx.y;
    const int t = threadIdx.x;
    const int w = t >> 6;          // wave id
    const int l = t & 63;
    const int g = l >> 5;          // k-group within wave (0/1)
    const int ln31 = l & 31;       // A row / B col / D col

    // ---- W fragments in registers (waves 0..2), hi + lo
    bf16x8 wh[8], wl[8];
    if (w < 3) {
        const float* Wm = (w == 0) ? Wq : (w == 1) ? Wk : Wv;
        const float* wr = Wm + ln31 * CC;
        #pragma unroll
        for (int kt = 0; kt < 8; ++kt) {
            const int k0 = 16 * kt + 8 * g;
            #pragma unroll
            for (int j = 0; j < 8; ++j) {
                const float f = wr[k0 + j];
                const __bf16 h = (__bf16)f;
                wh[kt][j] = h;
                wl[kt][j] = (__bf16)(f - (float)h);
            }
        }
    }

    // wave-3 accumulators (KV and Ks), plus ones B-frag
    f32x16 kvA, ksA;
    bf16x8 ones;
    #pragma unroll
    for (int i = 0; i < 16; ++i) { kvA[i] = 0.f; ksA[i] = 0.f; }
    #pragma unroll
    for (int j = 0; j < 8; ++j) ones[j] = (__bf16)1.0f;

    // staging assignment: thread t -> pixel px, channel block cb (16 channels)
    const int px = t & 31;
    const int cb = t >> 5;        // 0..7

    const float* xbase = x + (size_t)b * CC * NN + (blockIdx.x << 9) + px;

    // ---- prologue: load + convert tile 0 into X[0]
    float xbuf[16];
    #pragma unroll
    for (int j = 0; j < 16; ++j)
        xbuf[j] = xbase[(size_t)(cb * 16 + j) * NN];
    {
        __bf16 hbuf[16], lbuf[16];
        #pragma unroll
        for (int j = 0; j < 16; ++j) {
            const float f = xbuf[j];
            const __bf16 h = (__bf16)f;
            hbuf[j] = h;
            lbuf[j] = (__bf16)(f - (float)h);
        }
        *(bf16x8*)&Xh[px * 136 + cb * 16]     = *(bf16x8*)&hbuf[0];
        *(bf16x8*)&Xh[px * 136 + cb * 16 + 8] = *(bf16x8*)&hbuf[8];
        *(bf16x8*)&Xl[px * 136 + cb * 16]     = *(bf16x8*)&lbuf[0];
        *(bf16x8*)&Xl[px * 136 + cb * 16 + 8] = *(bf16x8*)&lbuf[8];
    }
    __syncthreads();

    for (int tile = 0; tile < 16; ++tile) {
        const int cur = tile & 1;
        const int n0 = (blockIdx.x << 9) + (tile << 5);

        // ---- phase 1: loads(t+1) || proj MFMA(t) [w0-2] || KV MFMA(t-1) [w3]
        if (tile < 15) {
            const float* xp = xbase + ((tile + 1) << 5);
            #pragma unroll
            for (int j = 0; j < 16; ++j)
                xbuf[j] = xp[(size_t)(cb * 16 + j) * NN];
        }

        f32x16 acc;
        if (w < 3) {
            #pragma unroll
            for (int i = 0; i < 16; ++i) acc[i] = 0.f;
            const __bf16* xh = Xh + cur * 4352 + ln31 * 136;
            const __bf16* xl = Xl + cur * 4352 + ln31 * 136;
            #pragma unroll
            for (int kt = 0; kt < 8; ++kt) {
                const int k0 = 16 * kt + 8 * g;
                const bf16x8 bh = *(const bf16x8*)&xh[k0];
                const bf16x8 bl = *(const bf16x8*)&xl[k0];
                acc = __builtin_amdgcn_mfma_f32_32x32x16_bf16(wh[kt], bh, acc, 0, 0, 0);
                acc = __builtin_amdgcn_mfma_f32_32x32x16_bf16(wh[kt], bl, acc, 0, 0, 0);
                acc = __builtin_amdgcn_mfma_f32_32x32x16_bf16(wl[kt], bh, acc, 0, 0, 0);
            }
        } else if (tile > 0) {
            const int pbuf = (cur ^ 1) * 1280;
            const __bf16* khp = ktH + pbuf + ln31 * 40;
            const __bf16* klp = ktL + pbuf + ln31 * 40;
            const __bf16* vhp = vtH + pbuf + ln31 * 40;
            const __bf16* vlp = vtL + pbuf + ln31 * 40;
            #pragma unroll
            for (int s = 0; s < 2; ++s) {
                const int k0 = s * 16 + g * 8;
                const bf16x8 akh = *(const bf16x8*)&khp[k0];
                const bf16x8 akl = *(const bf16x8*)&klp[k0];
                const bf16x8 bvh = *(const bf16x8*)&vhp[k0];
                const bf16x8 bvl = *(const bf16x8*)&vlp[k0];
                kvA = __builtin_amdgcn_mfma_f32_32x32x16_bf16(akh, bvh, kvA, 0, 0, 0);
                kvA = __builtin_amdgcn_mfma_f32_32x32x16_bf16(akh, bvl, kvA, 0, 0, 0);
                kvA = __builtin_amdgcn_mfma_f32_32x32x16_bf16(akl, bvh, kvA, 0, 0, 0);
                ksA = __builtin_amdgcn_mfma_f32_32x32x16_bf16(akh, ones, ksA, 0, 0, 0);
                ksA = __builtin_amdgcn_mfma_f32_32x32x16_bf16(akl, ones, ksA, 0, 0, 0);
            }
        }

        // ---- phase 2: write outputs of tile t, stage X for tile t+1
        if (w == 0) {
            float* qp = qout + (size_t)b * CC * NN + n0 + ln31;
            #pragma unroll
            for (int i = 0; i < 16; ++i) {
                const int r = (i & 3) + 8 * (i >> 2) + 4 * g;
                qp[(size_t)r * NN] = phi_f(acc[i]);
            }
        } else if (w == 1) {
            __bf16* kh = ktH + cur * 1280;
            __bf16* kl = ktL + cur * 1280;
            #pragma unroll
            for (int i = 0; i < 16; ++i) {
                const int r = (i & 3) + 8 * (i >> 2) + 4 * g;
                const float f = phi_f(acc[i]);
                const __bf16 h = (__bf16)f;
                kh[r * 40 + ln31] = h;
                kl[r * 40 + ln31] = (__bf16)(f - (float)h);
            }
        } else if (w == 2) {
            __bf16* vh = vtH + cur * 1280;
            __bf16* vl = vtL + cur * 1280;
            #pragma unroll
            for (int i = 0; i < 16; ++i) {
                const int r = (i & 3) + 8 * (i >> 2) + 4 * g;
                const float f = acc[i];
                const __bf16 h = (__bf16)f;
                vh[r * 40 + ln31] = h;
                vl[r * 40 + ln31] = (__bf16)(f - (float)h);
            }
        }

        if (tile < 15) {
            const int nxt = cur ^ 1;
            __bf16 hbuf[16], lbuf[16];
            #pragma unroll
            for (int j = 0; j < 16; ++j) {
                const float f = xbuf[j];
                const __bf16 h = (__bf16)f;
                hbuf[j] = h;
                lbuf[j] = (__bf16)(f - (float)h);
            }
            *(bf16x8*)&Xh[nxt * 4352 + px * 136 + cb * 16]     = *(bf16x8*)&hbuf[0];
            *(bf16x8*)&Xh[nxt * 4352 + px * 136 + cb * 16 + 8] = *(bf16x8*)&hbuf[8];
            *(bf16x8*)&Xl[nxt * 4352 + px * 136 + cb * 16]     = *(bf16x8*)&lbuf[0];
            *(bf16x8*)&Xl[nxt * 4352 + px * 136 + cb * 16 + 8] = *(bf16x8*)&lbuf[8];
        }
        __syncthreads();
    }

    // ---- epilogue (wave 3 only): KV/Ks for tile 15 (buffer 1), then atomics
    if (w == 3) {
        const int pbuf = 1280;
        const __bf16* khp = ktH + pbuf + ln31 * 40;
        const __bf16* klp = ktL + pbuf + ln31 * 40;
        const __bf16* vhp = vtH + pbuf + ln31 * 40;
        const __bf16* vlp = vtL + pbuf + ln31 * 40;
        #pragma unroll
        for (int s = 0; s < 2; ++s) {
            const int k0 = s * 16 + g * 8;
            const bf16x8 akh = *(const bf16x8*)&khp[k0];
            const bf16x8 akl = *(const bf16x8*)&klp[k0];
            const bf16x8 bvh = *(const bf16x8*)&vhp[k0];
            const bf16x8 bvl = *(const bf16x8*)&vlp[k0];
            kvA = __builtin_amdgcn_mfma_f32_32x32x16_bf16(akh, bvh, kvA, 0, 0, 0);
            kvA = __builtin_amdgcn_mfma_f32_32x32x16_bf16(akh, bvl, kvA, 0, 0, 0);
            kvA = __builtin_amdgcn_mfma_f32_32x32x16_bf16(akl, bvh, kvA, 0, 0, 0);
            ksA = __builtin_amdgcn_mfma_f32_32x32x16_bf16(akh, ones, ksA, 0, 0, 0);
            ksA = __builtin_amdgcn_mfma_f32_32x32x16_bf16(akl, ones, ksA, 0, 0, 0);
        }
        float* kvb = ws + WS_KV + (b << 10);
        #pragma unroll
        for (int i = 0; i < 16; ++i) {
            const int r = (i & 3) + 8 * (i >> 2) + 4 * g;
            atomicAdd(&kvb[r * 32 + ln31], kvA[i]);
        }
        if (ln31 == 0) {
            #pragma unroll
            for (int i = 0; i < 16; ++i) {
                const int r = (i & 3) + 8 * (i >> 2) + 4 * g;
                atomicAdd(&ws[WS_KS + (b << 5) + r], ksA[i]);
            }
        }
    }
}

// ---------------------------------------------------------------------------
// Pass C: read phi(Q), fold inv; accumulate Sq[b], QQ[b].
// grid (64,16) x 256, one 256-px tile per block.
__global__ __launch_bounds__(256) void qq_kernel(const float* qsrc, float* ws) {
    __shared__ __align__(16) float qt[256 * 36];

    const int b = blockIdx.y;
    const int t = threadIdx.x;
    const int l = t & 63;
    const int g = t >> 6;
    const int m0 = (l >> 3) << 2;
    const int v0 = (l & 7) << 2;

    float qqacc[16];
    #pragma unroll
    for (int i = 0; i < 16; ++i) qqacc[i] = 0.f;
    float sqacc[4] = {0.f, 0.f, 0.f, 0.f};

    const float* ksb = ws + WS_KS + (b << 5);

    const int n = (blockIdx.x << 8) + t;
    const float* qp = qsrc + (size_t)b * CC * NN + n;
    float qa[32];
    #pragma unroll
    for (int m = 0; m < 32; ++m) qa[m] = qp[(size_t)m * NN];

    float denom = 1e-6f;
    #pragma unroll
    for (int m = 0; m < 32; ++m) denom = fmaf(qa[m], ksb[m], denom);
    const float inv = 1.0f / (16384.0f * denom);
    #pragma unroll
    for (int m = 0; m < 32; ++m) qa[m] *= inv;

    #pragma unroll
    for (int q = 0; q < 8; ++q)
        *(float4*)&qt[t * 36 + 4*q] = *(float4*)&qa[4*q];
    __syncthreads();

    const int pbase = g << 6;
    for (int pp = 0; pp < 64; ++pp) {
        const int p = pbase + pp;
        const float4 uf = *(const float4*)&qt[p * 36 + m0];
        const float4 vf = *(const float4*)&qt[p * 36 + v0];
        qqacc[ 0] = fmaf(uf.x, vf.x, qqacc[ 0]);
        qqacc[ 1] = fmaf(uf.x, vf.y, qqacc[ 1]);
        qqacc[ 2] = fmaf(uf.x, vf.z, qqacc[ 2]);
        qqacc[ 3] = fmaf(uf.x, vf.w, qqacc[ 3]);
        qqacc[ 4] = fmaf(uf.y, vf.x, qqacc[ 4]);
        qqacc[ 5] = fmaf(uf.y, vf.y, qqacc[ 5]);
        qqacc[ 6] = fmaf(uf.y, vf.z, qqacc[ 6]);
        qqacc[ 7] = fmaf(uf.y, vf.w, qqacc[ 7]);
        qqacc[ 8] = fmaf(uf.z, vf.x, qqacc[ 8]);
        qqacc[ 9] = fmaf(uf.z, vf.y, qqacc[ 9]);
        qqacc[10] = fmaf(uf.z, vf.z, qqacc[10]);
        qqacc[11] = fmaf(uf.z, vf.w, qqacc[11]);
        qqacc[12] = fmaf(uf.w, vf.x, qqacc[12]);
        qqacc[13] = fmaf(uf.w, vf.y, qqacc[13]);
        qqacc[14] = fmaf(uf.w, vf.z, qqacc[14]);
        qqacc[15] = fmaf(uf.w, vf.w, qqacc[15]);
        if (v0 == 0) {
            sqacc[0] += uf.x; sqacc[1] += uf.y;
            sqacc[2] += uf.z; sqacc[3] += uf.w;
        }
    }

    __syncthreads();
    #pragma unroll
    for (int i = 0; i < 16; ++i) qt[t * 17 + i] = qqacc[i];
    if (v0 == 0) {
        const int r = l >> 3;
        #pragma unroll
        for (int i = 0; i < 4; ++i) qt[4352 + (g * 8 + r) * 4 + i] = sqacc[i];
    }
    __syncthreads();
    if (t < 64) {
        float* qqb = ws + WS_QQ + (b << 10);
        #pragma unroll
        for (int i = 0; i < 16; ++i) {
            const float s = qt[t*17+i] + qt[(t+64)*17+i] + qt[(t+128)*17+i] + qt[(t+192)*17+i];
            atomicAdd(&qqb[(m0 + (i >> 2)) * 32 + v0 + (i & 3)], s);
        }
    }
    if (t < 8) {
        #pragma unroll
        for (int i = 0; i < 4; ++i) {
            const float s = qt[4352 + t*4+i] + qt[4352 + (8+t)*4+i]
                          + qt[4352 + (16+t)*4+i] + qt[4352 + (24+t)*4+i];
            atomicAdd(&ws[WS_SQ + (b << 5) + t * 4 + i], s);
        }
    }
}

// ---------------------------------------------------------------------------
// Merged W2 + BN stats: w2row = Wout[c]·KV[b] (stored for out_kernel), then
// ysum_c += w2·Sq_b ; ysq_c += w2·QQ_b·w2^T.
__global__ __launch_bounds__(128) void bnstat_kernel(const float* __restrict__ Wout,
                                                     float* ws) {
    const int b = blockIdx.x;   // 16
    const int c = threadIdx.x;  // 128
    const float* kvb = ws + WS_KV + (b << 10);
    const float* wo  = Wout + (c << 5);
    float w[32];
    #pragma unroll
    for (int v = 0; v < 32; ++v) w[v] = 0.f;
    for (int m = 0; m < 32; ++m) {
        const float wm = wo[m];
        #pragma unroll
        for (int v = 0; v < 32; ++v) w[v] = fmaf(wm, kvb[(m << 5) + v], w[v]);
    }
    float* w2b = ws + WS_W2 + (b << 12) + (c << 5);
    #pragma unroll
    for (int v = 0; v < 32; ++v) w2b[v] = w[v];

    const float* sq = ws + WS_SQ + (b << 5);
    const float* qq = ws + WS_QQ + (b << 10);
    float mb = 0.f;
    #pragma unroll
    for (int v = 0; v < 32; ++v) mb = fmaf(w[v], sq[v], mb);
    float qf = 0.f;
    for (int u = 0; u < 32; ++u) {
        float tacc = 0.f;
        #pragma unroll
        for (int v = 0; v < 32; ++v) tacc = fmaf(qq[(u << 5) + v], w[v], tacc);
        qf = fmaf(w[u], tacc, qf);
    }
    atomicAdd(&ws[WS_YSUM + c], mb);
    atomicAdd(&ws[WS_YSQ + c], qf);
}

// ---------------------------------------------------------------------------
// Output via MFMA with inline BN finalize: y = scale_c*(W2[c]·Q'_n) + bias_c.
// scale/bias computed per-block from ysum/ysq moments (128 rsqrt, cheap).
__global__ __launch_bounds__(256) void out_kernel(const float* qsrc, const float* ws,
                                                  const float* __restrict__ gamma,
                                                  const float* __restrict__ beta,
                                                  float* out) {
    __shared__ __align__(16) __bf16 Qh[256 * 36];  // 18 KB
    __shared__ __align__(16) __bf16 Ql[256 * 36];  // 18 KB
    __shared__ float scs[CC];
    __shared__ float bis[CC];

    const int b = blockIdx.y;
    const int t = threadIdx.x;
    const int w = t >> 6;
    const int l = t & 63;
    const int g = l >> 5;
    const int ln31 = l & 31;

    if (t < CC) {
        const float invBN = 1.0f / 262144.0f;
        const float mean = ws[WS_YSUM + t] * invBN;
        const float var  = ws[WS_YSQ + t] * invBN - mean * mean;
        const float s = gamma[t] * rsqrtf(var + 1e-5f);
        scs[t] = s;
        bis[t] = fmaf(-mean, s, beta[t]);
    }

    const int n = (blockIdx.x << 8) + t;
    const float* ksb = ws + WS_KS + (b << 5);

    // ---- stage: load this px's Q, fold inv, convert to bf16 hi/lo in LDS
    const float* qp = qsrc + (size_t)b * CC * NN + n;
    float qa[32];
    #pragma unroll
    for (int m = 0; m < 32; ++m) qa[m] = qp[(size_t)m * NN];

    float d0 = 1e-6f;
    #pragma unroll
    for (int m = 0; m < 32; ++m) d0 = fmaf(qa[m], ksb[m], d0);
    const float inv = 1.0f / (16384.0f * d0);
    #pragma unroll
    for (int m = 0; m < 32; ++m) qa[m] *= inv;

    {
        __bf16 qh[32], ql[32];
        #pragma unroll
        for (int m = 0; m < 32; ++m) {
            const __bf16 h = (__bf16)qa[m];
            qh[m] = h;
            ql[m] = (__bf16)(qa[m] - (float)h);
        }
        #pragma unroll
        for (int i = 0; i < 8; ++i) {
            *(bf16x4*)&Qh[t * 36 + i * 4] = *(bf16x4*)&qh[i * 4];
            *(bf16x4*)&Ql[t * 36 + i * 4] = *(bf16x4*)&ql[i * 4];
        }
    }
    __syncthreads();

    const float* w2b = ws + WS_W2 + (b << 12);
    float* ob = out + (size_t)b * CC * NN + (blockIdx.x << 8);

    #pragma unroll
    for (int cb = 0; cb < 4; ++cb) {
        bf16x8 ah[2], al[2];
        #pragma unroll
        for (int kt = 0; kt < 2; ++kt) {
            const float* wp = w2b + (cb * 32 + ln31) * 32 + kt * 16 + g * 8;
            #pragma unroll
            for (int j = 0; j < 8; ++j) {
                const float f = wp[j];
                const __bf16 h = (__bf16)f;
                ah[kt][j] = h;
                al[kt][j] = (__bf16)(f - (float)h);
            }
        }
        #pragma unroll
        for (int pg = 0; pg < 2; ++pg) {
            const int px0 = (w << 6) + (pg << 5);    // wave-private rows
            f32x16 acc;
            #pragma unroll
            for (int i = 0; i < 16; ++i) acc[i] = 0.f;
            #pragma unroll
            for (int kt = 0; kt < 2; ++kt) {
                const int k0 = kt * 16 + g * 8;
                const __bf16* qhp = &Qh[(px0 + ln31) * 36 + k0];
                const __bf16* qlp = &Ql[(px0 + ln31) * 36 + k0];
                B8 bh, bl;
                bh.v4[0] = *(const bf16x4*)&qhp[0];
                bh.v4[1] = *(const bf16x4*)&qhp[4];
                bl.v4[0] = *(const bf16x4*)&qlp[0];
                bl.v4[1] = *(const bf16x4*)&qlp[4];
                acc = __builtin_amdgcn_mfma_f32_32x32x16_bf16(ah[kt], bh.v8, acc, 0, 0, 0);
                acc = __builtin_amdgcn_mfma_f32_32x32x16_bf16(ah[kt], bl.v8, acc, 0, 0, 0);
                acc = __builtin_amdgcn_mfma_f32_32x32x16_bf16(al[kt], bh.v8, acc, 0, 0, 0);
            }
            #pragma unroll
            for (int i = 0; i < 16; ++i) {
                const int r = (i & 3) + 8 * (i >> 2) + 4 * g;
                const int c = cb * 32 + r;
                const float v = fmaf(scs[c], acc[i], bis[c]);
                __builtin_nontemporal_store(v, &ob[(size_t)c * NN + px0 + ln31]);
            }
        }
    }
}

// ---------------------------------------------------------------------------
extern "C" void kernel_launch(void* const* d_in, const int* in_sizes, int n_in,
                              void* d_out, int out_size, void* d_ws, size_t ws_size,
                              hipStream_t stream) {
    const float* x     = (const float*)d_in[0];
    const float* Wq    = (const float*)d_in[1];
    const float* Wk    = (const float*)d_in[2];
    const float* Wv    = (const float*)d_in[3];
    const float* Wout  = (const float*)d_in[4];
    const float* gamma = (const float*)d_in[5];
    const float* beta  = (const float*)d_in[6];
    float* ws  = (float*)d_ws;
    float* out = (float*)d_out;

    zero_kernel<<<34, 256, 0, stream>>>(ws);
    projmfma_kernel<<<dim3(32, 16), 256, 0, stream>>>(x, Wq, Wk, Wv, ws, out);
    qq_kernel<<<dim3(64, 16), 256, 0, stream>>>(out, ws);
    bnstat_kernel<<<16, 128, 0, stream>>>(Wout, ws);
    out_kernel<<<dim3(64, 16), 256, 0, stream>>>(out, ws, gamma, beta, out);
}